// Round 15
// baseline (460.531 us; speedup 1.0000x reference)
//
#include <hip/hip_runtime.h>
#include <hip/hip_bf16.h>

// ---------------------------------------------------------------------------
// TransformerBlock forward, MI355X (gfx950).
// B=2, S=2048, D=2048, HQ=32 (group-summed into 8), HKV=8, DH=64, DMLP=8192.
// Round-15: woutT transpose folded into the FFN1 launch as trailing blocks
// (runs in FFN1's tail: overlapped with late GEMM blocks, minimal traffic
// before FFN2's read -> L3-hot). Dedicated woutT region guarded on ws_size
// (>=187MB verified in round 11); fallback = round-14 serial path.
// ---------------------------------------------------------------------------

using bf16 = __hip_bfloat16;
typedef __bf16 bf16x8_t __attribute__((ext_vector_type(8)));
typedef float  f32x4_t  __attribute__((ext_vector_type(4)));

#define D_MODEL 2048
#define SEQ     2048
#define NB      2
#define NTOK    4096
#define NKV     8
#define DHEAD   64
#define DMLP    8192
#define NQKV    1536

__device__ inline void storev(float* p, float v) { *p = v; }
__device__ inline void storev(bf16* p, float v)  { *p = __float2bfloat16(v); }

__device__ inline bf16 h_from_b(__bf16 x) {
    union { __bf16 b; bf16 h; } u;
    u.b = x;
    return u.h;
}

// ---------------------------------------------------------------------------
// Standalone transpose (fallback path for woutT).
// ---------------------------------------------------------------------------
__global__ __launch_bounds__(256) void transpose_f32_bf16_kernel(
    const float* __restrict__ in, bf16* __restrict__ out, int K, int N)
{
    __shared__ float tile[32][33];
    const int n0 = blockIdx.x * 32, k0 = blockIdx.y * 32;
    const int tx = threadIdx.x & 31, ty = threadIdx.x >> 5;
    #pragma unroll
    for (int i = 0; i < 32; i += 8)
        tile[ty + i][tx] = in[(size_t)(k0 + ty + i) * N + n0 + tx];
    __syncthreads();
    #pragma unroll
    for (int i = 0; i < 32; i += 8)
        out[(size_t)(n0 + ty + i) * K + k0 + tx] = __float2bfloat16(tile[tx][ty + i]);
}

// ---------------------------------------------------------------------------
// Standalone rmsnorm (rmsnorm2).
// ---------------------------------------------------------------------------
__global__ __launch_bounds__(256) void rmsnorm_kernel(
    const float* __restrict__ x, const float* __restrict__ g,
    const float* __restrict__ b, bf16* __restrict__ out)
{
    const int row = blockIdx.x;
    const int t = threadIdx.x;
    const float* xr = x + (size_t)row * D_MODEL;
    float4 a0 = *reinterpret_cast<const float4*>(xr + t * 8);
    float4 a1 = *reinterpret_cast<const float4*>(xr + t * 8 + 4);
    float v[8] = {a0.x, a0.y, a0.z, a0.w, a1.x, a1.y, a1.z, a1.w};
    float sum = 0.f, sumsq = 0.f;
    #pragma unroll
    for (int j = 0; j < 8; ++j) { sum += v[j]; sumsq += v[j] * v[j]; }
    #pragma unroll
    for (int o = 1; o < 64; o <<= 1) {
        sum   += __shfl_xor(sum, o);
        sumsq += __shfl_xor(sumsq, o);
    }
    __shared__ float rs[4], rq[4];
    if ((t & 63) == 0) { rs[t >> 6] = sum; rq[t >> 6] = sumsq; }
    __syncthreads();
    sum   = rs[0] + rs[1] + rs[2] + rs[3];
    sumsq = rq[0] + rq[1] + rq[2] + rq[3];
    const float mu  = sum * (1.f / D_MODEL);
    const float var = sumsq * (1.f / D_MODEL) - mu * mu;
    const float rstd = 1.f / sqrtf(var + 1e-5f);
    const int c = t * 8;
    float4 g0 = *reinterpret_cast<const float4*>(g + c);
    float4 g1 = *reinterpret_cast<const float4*>(g + c + 4);
    float4 b0 = *reinterpret_cast<const float4*>(b + c);
    float4 b1 = *reinterpret_cast<const float4*>(b + c + 4);
    float gg[8] = {g0.x, g0.y, g0.z, g0.w, g1.x, g1.y, g1.z, g1.w};
    float bb[8] = {b0.x, b0.y, b0.z, b0.w, b1.x, b1.y, b1.z, b1.w};
    bf16* op = out + (size_t)row * D_MODEL + c;
    #pragma unroll
    for (int j = 0; j < 8; ++j) op[j] = __float2bfloat16(v[j] * rstd * gg[j] + bb[j]);
}

// ---------------------------------------------------------------------------
// fusedA: blocks [0,4096) rmsnorm1 ; [4096,5632) head-transposes Q/K/V ;
// [5632,6656) woT transpose. 256 thr, 8.3KB LDS union.
// ---------------------------------------------------------------------------
__global__ __launch_bounds__(256) void fusedA_kernel(
    const float* __restrict__ resid_pre, const float* __restrict__ g1,
    const float* __restrict__ b1, bf16* __restrict__ x1,
    const float* __restrict__ WQ, const float* __restrict__ WK,
    const float* __restrict__ WV, bf16* __restrict__ wqkvT,
    const float* __restrict__ WO, bf16* __restrict__ woT)
{
    __shared__ __align__(16) float smem[32 * 65];
    const int id = blockIdx.x;
    const int t  = threadIdx.x;

    if (id < 4096) {
        float* rs = smem;
        float* rq = smem + 4;
        const float* xr = resid_pre + (size_t)id * D_MODEL;
        float4 a0 = *reinterpret_cast<const float4*>(xr + t * 8);
        float4 a1 = *reinterpret_cast<const float4*>(xr + t * 8 + 4);
        float v[8] = {a0.x, a0.y, a0.z, a0.w, a1.x, a1.y, a1.z, a1.w};
        float sum = 0.f, sumsq = 0.f;
        #pragma unroll
        for (int j = 0; j < 8; ++j) { sum += v[j]; sumsq += v[j] * v[j]; }
        #pragma unroll
        for (int o = 1; o < 64; o <<= 1) {
            sum   += __shfl_xor(sum, o);
            sumsq += __shfl_xor(sumsq, o);
        }
        if ((t & 63) == 0) { rs[t >> 6] = sum; rq[t >> 6] = sumsq; }
        __syncthreads();
        sum   = rs[0] + rs[1] + rs[2] + rs[3];
        sumsq = rq[0] + rq[1] + rq[2] + rq[3];
        const float mu  = sum * (1.f / D_MODEL);
        const float var = sumsq * (1.f / D_MODEL) - mu * mu;
        const float rstd = 1.f / sqrtf(var + 1e-5f);
        const int c = t * 8;
        float4 g0 = *reinterpret_cast<const float4*>(g1 + c);
        float4 g1v = *reinterpret_cast<const float4*>(g1 + c + 4);
        float4 b0 = *reinterpret_cast<const float4*>(b1 + c);
        float4 b1v = *reinterpret_cast<const float4*>(b1 + c + 4);
        float gg[8] = {g0.x, g0.y, g0.z, g0.w, g1v.x, g1v.y, g1v.z, g1v.w};
        float bb[8] = {b0.x, b0.y, b0.z, b0.w, b1v.x, b1v.y, b1v.z, b1v.w};
        bf16* op = x1 + (size_t)id * D_MODEL + c;
        #pragma unroll
        for (int j = 0; j < 8; ++j) op[j] = __float2bfloat16(v[j] * rstd * gg[j] + bb[j]);
    } else if (id < 5632) {
        int sub = id - 4096;
        const int which = sub >> 9;
        sub &= 511;
        const float* in = which == 0 ? WQ : (which == 1 ? WK : WV);
        bf16* outp = wqkvT + (size_t)which * 512 * D_MODEL;
        const int ngroup = which == 0 ? 4 : 1;
        const int kv = sub >> 6;
        const int k0 = (sub & 63) * 32;
        float (*tile)[65] = reinterpret_cast<float(*)[65]>(smem);
        const int e  = t & 63, kk = t >> 6;
        #pragma unroll
        for (int i = 0; i < 32; i += 4) {
            float s = 0.f;
            for (int g = 0; g < ngroup; ++g)
                s += in[((size_t)(kv * ngroup + g) * 2048 + k0 + kk + i) * 64 + e];
            tile[kk + i][e] = s;
        }
        __syncthreads();
        const int k = t & 31, ee = t >> 5;
        #pragma unroll
        for (int i = 0; i < 64; i += 8)
            outp[(size_t)(kv * 64 + ee + i) * 2048 + k0 + k] = __float2bfloat16(tile[k][ee + i]);
    } else {
        const int sub = id - 5632;
        const int n0 = (sub & 63) * 32, k0 = (sub >> 6) * 32;
        float (*tile)[33] = reinterpret_cast<float(*)[33]>(smem);
        const int tx = t & 31, ty = t >> 5;
        #pragma unroll
        for (int i = 0; i < 32; i += 8)
            tile[ty + i][tx] = WO[(size_t)(k0 + ty + i) * D_MODEL + n0 + tx];
        __syncthreads();
        #pragma unroll
        for (int i = 0; i < 32; i += 8)
            woT[(size_t)(n0 + ty + i) * 512 + k0 + tx] = __float2bfloat16(tile[tx][ty + i]);
    }
}

// ---------------------------------------------------------------------------
// 2-phase pipelined GEMM (verified): QKV / proj / FFN2.
// ---------------------------------------------------------------------------
template<int BM, int BN, typename TC, bool BIAS, bool RELU, bool RESID>
__global__ __launch_bounds__(512, 2) void gemm_pipe_kernel(
    const bf16* __restrict__ A, const bf16* __restrict__ Bt,
    TC* __restrict__ C, const float* __restrict__ bias,
    const float* __restrict__ resid, int M, int N, int K, int nbx)
{
    constexpr int BK   = 64;
    constexpr int MREP = BM / 32;
    constexpr int NREP = BN / 64;
    constexpr int AI   = (BM * BK) / 4096;
    constexpr int BI   = (BN * BK) / 4096;
    constexpr int LD   = AI + BI;

    __shared__ __align__(16) bf16 As[2][BM * BK];
    __shared__ __align__(16) bf16 Bs[2][BN * BK];

    const int nwg = gridDim.x;
    const int swz = (blockIdx.x & 7) * (nwg >> 3) + (blockIdx.x >> 3);
    const int nby = nwg / nbx;
    const int by  = swz % nby;
    const int bx  = swz / nby;
    const int row0 = by * BM, col0 = bx * BN;

    const int t  = threadIdx.x;
    const int w  = t >> 6, ln = t & 63;
    const int wm = w >> 2, wn = w & 3;
    const int lr = ln & 15, hi = ln >> 4;

    const int srow = w * 8 + (ln >> 3);
    const int skx  = ((ln & 7) ^ (ln >> 3)) * 8;

    f32x4_t acc[MREP][NREP];
    #pragma unroll
    for (int m = 0; m < MREP; ++m)
        #pragma unroll
        for (int n = 0; n < NREP; ++n) acc[m][n] = (f32x4_t){0.f, 0.f, 0.f, 0.f};

    const int NT = K / BK;

    {
        const bf16* ga = A  + (size_t)(row0 + srow) * K + skx;
        const bf16* gb = Bt + (size_t)(col0 + srow) * K + skx;
        #pragma unroll
        for (int i = 0; i < AI; ++i)
            __builtin_amdgcn_global_load_lds(
                (const __attribute__((address_space(1))) void*)(ga + (size_t)i * 64 * K),
                (__attribute__((address_space(3))) void*)(&As[0][i * 4096 + w * 512]), 16, 0, 0);
        #pragma unroll
        for (int i = 0; i < BI; ++i)
            __builtin_amdgcn_global_load_lds(
                (const __attribute__((address_space(1))) void*)(gb + (size_t)i * 64 * K),
                (__attribute__((address_space(3))) void*)(&Bs[0][i * 4096 + w * 512]), 16, 0, 0);
    }

    for (int tt = 0; tt < NT; ++tt) {
        const int c = tt & 1;
        asm volatile("s_waitcnt lgkmcnt(0)" ::: "memory");
        __builtin_amdgcn_sched_barrier(0);
        __builtin_amdgcn_s_barrier();
        __builtin_amdgcn_sched_barrier(0);
        if (tt + 1 < NT) {
            const int d = c ^ 1;
            const int kt = (tt + 1) * BK;
            const bf16* ga = A  + (size_t)(row0 + srow) * K + kt + skx;
            const bf16* gb = Bt + (size_t)(col0 + srow) * K + kt + skx;
            #pragma unroll
            for (int i = 0; i < AI; ++i)
                __builtin_amdgcn_global_load_lds(
                    (const __attribute__((address_space(1))) void*)(ga + (size_t)i * 64 * K),
                    (__attribute__((address_space(3))) void*)(&As[d][i * 4096 + w * 512]), 16, 0, 0);
            #pragma unroll
            for (int i = 0; i < BI; ++i)
                __builtin_amdgcn_global_load_lds(
                    (const __attribute__((address_space(1))) void*)(gb + (size_t)i * 64 * K),
                    (__attribute__((address_space(3))) void*)(&Bs[d][i * 4096 + w * 512]), 16, 0, 0);
            __builtin_amdgcn_sched_barrier(0);
            if constexpr (LD == 8)      asm volatile("s_waitcnt vmcnt(8)" ::: "memory");
            else if constexpr (LD == 6) asm volatile("s_waitcnt vmcnt(6)" ::: "memory");
            else if constexpr (LD == 4) asm volatile("s_waitcnt vmcnt(4)" ::: "memory");
            else                        asm volatile("s_waitcnt vmcnt(3)" ::: "memory");
        } else {
            asm volatile("s_waitcnt vmcnt(0)" ::: "memory");
        }
        __builtin_amdgcn_sched_barrier(0);
        __builtin_amdgcn_s_barrier();
        __builtin_amdgcn_sched_barrier(0);

        #pragma unroll
        for (int kk = 0; kk < 2; ++kk) {
            bf16x8_t af[MREP], bfr[NREP];
            #pragma unroll
            for (int m = 0; m < MREP; ++m) {
                const int row = wm * (BM / 2) + m * 16 + lr;
                af[m] = *reinterpret_cast<const bf16x8_t*>(
                    &As[c][row * 64 + ((kk * 32 + hi * 8) ^ ((row & 7) << 3))]);
            }
            #pragma unroll
            for (int n = 0; n < NREP; ++n) {
                const int col = wn * (BN / 4) + n * 16 + lr;
                bfr[n] = *reinterpret_cast<const bf16x8_t*>(
                    &Bs[c][col * 64 + ((kk * 32 + hi * 8) ^ ((col & 7) << 3))]);
            }
            #pragma unroll
            for (int m = 0; m < MREP; ++m)
                #pragma unroll
                for (int n = 0; n < NREP; ++n)
                    acc[m][n] = __builtin_amdgcn_mfma_f32_16x16x32_bf16(af[m], bfr[n], acc[m][n], 0, 0, 0);
        }
    }

    #pragma unroll
    for (int m = 0; m < MREP; ++m) {
        #pragma unroll
        for (int n = 0; n < NREP; ++n) {
            const int cgl = col0 + wn * (BN / 4) + n * 16 + lr;
            #pragma unroll
            for (int j = 0; j < 4; ++j) {
                const int r = row0 + wm * (BM / 2) + m * 16 + hi * 4 + j;
                float v = acc[m][n][j];
                if constexpr (BIAS)  v += bias[cgl];
                if constexpr (RELU)  v = fmaxf(v, 0.f);
                if constexpr (RESID) v += resid[(size_t)r * N + cgl];
                storev(&C[(size_t)r * N + cgl], v);
            }
        }
    }
}

// ---------------------------------------------------------------------------
// 8-phase 256x256 GEMM for FFN1 (round-14 4-barrier variant) + optional
// trailing transpose blocks: blockIdx >= ngemm transposes Wt_src [8192][2048]
// f32 -> Wt_dst [2048][8192] bf16 in 64x64 tiles (runs in the GEMM tail,
// overlapped; woutT then L3-hot for FFN2). XCD swizzle uses ngemm, not grid.
// ---------------------------------------------------------------------------
template<typename TC, bool BIAS, bool RELU, bool RESID>
__global__ __launch_bounds__(512, 2) void gemm_8ph_kernel(
    const bf16* __restrict__ A, const bf16* __restrict__ Bt,
    TC* __restrict__ C, const float* __restrict__ bias,
    const float* __restrict__ resid, int M, int N, int K, int nbx,
    const float* __restrict__ Wt_src, bf16* __restrict__ Wt_dst, int ngemm)
{
    __shared__ __align__(16) bf16 As[2][256 * 64];
    __shared__ __align__(16) bf16 Bs[2][256 * 64];

    if ((int)blockIdx.x >= ngemm) {
        // ---- transpose role: 64x64 f32 tile, 512 thr, smem overlaid on As
        const int sub = blockIdx.x - ngemm;
        const int n0 = (sub & 31) * 64;          // over 2048
        const int k0 = (sub >> 5) * 64;          // over 8192
        float (*tile)[65] = reinterpret_cast<float(*)[65]>(&As[0][0]);
        const int tx = threadIdx.x & 63, ty = threadIdx.x >> 6;   // ty 0..7
        #pragma unroll
        for (int i = 0; i < 64; i += 8)
            tile[ty + i][tx] = Wt_src[(size_t)(k0 + ty + i) * D_MODEL + n0 + tx];
        __syncthreads();
        #pragma unroll
        for (int i = 0; i < 64; i += 8)
            Wt_dst[(size_t)(n0 + ty + i) * DMLP + k0 + tx] = __float2bfloat16(tile[tx][ty + i]);
        return;
    }

    const int nwg = ngemm;
    const int swz = (blockIdx.x & 7) * (nwg >> 3) + (blockIdx.x >> 3);
    const int nby = nwg / nbx;
    const int by  = swz % nby;
    const int bx  = swz / nby;
    const int row0 = by * 256, col0 = bx * 256;

    const int t  = threadIdx.x;
    const int w  = t >> 6, ln = t & 63;
    const int wm = w >> 2, wn = w & 3;
    const int lr = ln & 15, hi = ln >> 4;
    const int rx = (lr & 7) << 3;

    const int srow = w * 8 + (ln >> 3);
    const int skx  = ((ln & 7) ^ (ln >> 3)) * 8;

#define STAGE_A8(u, dbuf, kt)                                                   \
    __builtin_amdgcn_global_load_lds(                                           \
        (const __attribute__((address_space(1))) void*)(A + (size_t)(row0 + (u) * 64 + srow) * K + (kt) + skx), \
        (__attribute__((address_space(3))) void*)(&As[dbuf][(u) * 4096 + w * 512]), 16, 0, 0)
#define STAGE_B8(u, dbuf, kt)                                                   \
    __builtin_amdgcn_global_load_lds(                                           \
        (const __attribute__((address_space(1))) void*)(Bt + (size_t)(col0 + (u) * 64 + srow) * K + (kt) + skx), \
        (__attribute__((address_space(3))) void*)(&Bs[dbuf][(u) * 4096 + w * 512]), 16, 0, 0)
#define PH_BAR                                                                  \
    __builtin_amdgcn_sched_barrier(0);                                          \
    __builtin_amdgcn_s_barrier();                                               \
    __builtin_amdgcn_sched_barrier(0)
#define LGKM0                                                                   \
    asm volatile("s_waitcnt lgkmcnt(0)" ::: "memory");                          \
    __builtin_amdgcn_sched_barrier(0)

    f32x4_t acc[8][4];
    #pragma unroll
    for (int m = 0; m < 8; ++m)
        #pragma unroll
        for (int n = 0; n < 4; ++n) acc[m][n] = (f32x4_t){0.f, 0.f, 0.f, 0.f};

    bf16x8_t af[4][2];
    bf16x8_t af2[4][2];
    bf16x8_t bfr[4][2];

    const int NT = K / 64;

    STAGE_A8(0, 0, 0); STAGE_A8(2, 0, 0);
    STAGE_B8(0, 0, 0); STAGE_B8(1, 0, 0); STAGE_B8(2, 0, 0); STAGE_B8(3, 0, 0);
    STAGE_A8(1, 0, 0); STAGE_A8(3, 0, 0);
    asm volatile("s_waitcnt vmcnt(2)" ::: "memory");
    PH_BAR;

    for (int tt = 0; tt < NT; ++tt) {
        const int c  = tt & 1, d = c ^ 1;
        const int kn = (tt + 1) * 64;
        const bool pf = (tt + 1 < NT);

        // ---- phase 0 ----
        #pragma unroll
        for (int mq = 0; mq < 4; ++mq) {
            const int row = wm * 128 + mq * 16 + lr;
            #pragma unroll
            for (int kk = 0; kk < 2; ++kk)
                af[mq][kk] = *reinterpret_cast<const bf16x8_t*>(
                    &As[c][row * 64 + ((kk * 32 + hi * 8) ^ rx)]);
        }
        #pragma unroll
        for (int n = 0; n < 2; ++n) {
            const int col = wn * 64 + n * 16 + lr;
            #pragma unroll
            for (int kk = 0; kk < 2; ++kk)
                bfr[n][kk] = *reinterpret_cast<const bf16x8_t*>(
                    &Bs[c][col * 64 + ((kk * 32 + hi * 8) ^ rx)]);
        }
        if (pf) { STAGE_A8(0, d, kn); STAGE_A8(2, d, kn); }
        PH_BAR;
        LGKM0;
        __builtin_amdgcn_s_setprio(1);
        #pragma unroll
        for (int mq = 0; mq < 4; ++mq)
            #pragma unroll
            for (int n = 0; n < 2; ++n)
                #pragma unroll
                for (int kk = 0; kk < 2; ++kk)
                    acc[mq][n] = __builtin_amdgcn_mfma_f32_16x16x32_bf16(af[mq][kk], bfr[n][kk], acc[mq][n], 0, 0, 0);
        __builtin_amdgcn_s_setprio(0);

        // ---- phase 1 ----
        #pragma unroll
        for (int n = 2; n < 4; ++n) {
            const int col = wn * 64 + n * 16 + lr;
            #pragma unroll
            for (int kk = 0; kk < 2; ++kk)
                bfr[n][kk] = *reinterpret_cast<const bf16x8_t*>(
                    &Bs[c][col * 64 + ((kk * 32 + hi * 8) ^ rx)]);
        }
        if (pf) { STAGE_B8(0, d, kn); STAGE_B8(1, d, kn); }
        __builtin_amdgcn_sched_barrier(0);
        if (pf) { asm volatile("s_waitcnt vmcnt(4)" ::: "memory"); }
        else    { asm volatile("s_waitcnt vmcnt(0)" ::: "memory"); }
        PH_BAR;
        LGKM0;
        __builtin_amdgcn_s_setprio(1);
        #pragma unroll
        for (int mq = 0; mq < 4; ++mq)
            #pragma unroll
            for (int n = 2; n < 4; ++n)
                #pragma unroll
                for (int kk = 0; kk < 2; ++kk)
                    acc[mq][n] = __builtin_amdgcn_mfma_f32_16x16x32_bf16(af[mq][kk], bfr[n][kk], acc[mq][n], 0, 0, 0);
        __builtin_amdgcn_s_setprio(0);

        // ---- phase 2 ----
        #pragma unroll
        for (int mq = 0; mq < 4; ++mq) {
            const int row = wm * 128 + 64 + mq * 16 + lr;
            #pragma unroll
            for (int kk = 0; kk < 2; ++kk)
                af2[mq][kk] = *reinterpret_cast<const bf16x8_t*>(
                    &As[c][row * 64 + ((kk * 32 + hi * 8) ^ rx)]);
        }
        if (pf) { STAGE_B8(2, d, kn); STAGE_B8(3, d, kn); }
        PH_BAR;
        LGKM0;
        __builtin_amdgcn_s_setprio(1);
        #pragma unroll
        for (int mq = 0; mq < 4; ++mq)
            #pragma unroll
            for (int n = 2; n < 4; ++n)
                #pragma unroll
                for (int kk = 0; kk < 2; ++kk)
                    acc[4 + mq][n] = __builtin_amdgcn_mfma_f32_16x16x32_bf16(af2[mq][kk], bfr[n][kk], acc[4 + mq][n], 0, 0, 0);
        __builtin_amdgcn_s_setprio(0);

        // ---- phase 3 ----
        if (pf) {
            STAGE_A8(1, d, kn); STAGE_A8(3, d, kn);
            __builtin_amdgcn_sched_barrier(0);
            asm volatile("s_waitcnt vmcnt(2)" ::: "memory");
        }
        PH_BAR;
        __builtin_amdgcn_s_setprio(1);
        #pragma unroll
        for (int mq = 0; mq < 4; ++mq)
            #pragma unroll
            for (int n = 0; n < 2; ++n)
                #pragma unroll
                for (int kk = 0; kk < 2; ++kk)
                    acc[4 + mq][n] = __builtin_amdgcn_mfma_f32_16x16x32_bf16(af2[mq][kk], bfr[n][kk], acc[4 + mq][n], 0, 0, 0);
        __builtin_amdgcn_s_setprio(0);
    }

    #pragma unroll
    for (int m = 0; m < 8; ++m) {
        #pragma unroll
        for (int n = 0; n < 4; ++n) {
            const int cgl = col0 + wn * 64 + n * 16 + lr;
            #pragma unroll
            for (int j = 0; j < 4; ++j) {
                const int r = row0 + wm * 128 + m * 16 + hi * 4 + j;
                float v = acc[m][n][j];
                if constexpr (BIAS)  v += bias[cgl];
                if constexpr (RELU)  v = fmaxf(v, 0.f);
                if constexpr (RESID) v += resid[(size_t)r * N + cgl];
                storev(&C[(size_t)r * N + cgl], v);
            }
        }
    }
#undef STAGE_A8
#undef STAGE_B8
#undef PH_BAR
#undef LGKM0
}

// ---------------------------------------------------------------------------
// fusedB: blocks [0,256) = attention (XCD-pair swizzled) ;
// blocks [256,16640) = winT transpose. 256 thr, 27.6KB LDS union.
// ---------------------------------------------------------------------------
#define KVBLK 64
#define LP    72

__global__ __launch_bounds__(256) void fusedB_kernel(
    const bf16* __restrict__ qkv, bf16* __restrict__ z,
    const float* __restrict__ W_in, bf16* __restrict__ winT)
{
    __shared__ __align__(16) char smem[3 * KVBLK * LP * 2];   // 27648 B

    if (blockIdx.x >= 256) {
        const int sub = blockIdx.x - 256;
        const int n0 = (sub & 255) * 32, k0 = (sub >> 8) * 32;
        float (*tile)[33] = reinterpret_cast<float(*)[33]>(smem);
        const int tx = threadIdx.x & 31, ty = threadIdx.x >> 5;
        #pragma unroll
        for (int i = 0; i < 32; i += 8)
            tile[ty + i][tx] = W_in[(size_t)(k0 + ty + i) * DMLP + n0 + tx];
        __syncthreads();
        #pragma unroll
        for (int i = 0; i < 32; i += 8)
            winT[(size_t)(n0 + ty + i) * D_MODEL + k0 + tx] = __float2bfloat16(tile[tx][ty + i]);
        return;
    }

    const int i_   = blockIdx.x;
    const int pair = (i_ & 7) | ((i_ >> 7) << 3);
    const int a    = (i_ >> 3) & 15;
    const int kv   = pair & 7;
    const int b    = pair >> 3;
    const int b2   = 31 - a;
    const int t  = threadIdx.x;
    const int w  = t >> 6;
    const int ln = t & 63;
    const int lr = ln & 15;
    const int hi = ln >> 4;
    const int lk = hi * 8;

    bf16* Ks = reinterpret_cast<bf16*>(smem);
    bf16* Vt = Ks + KVBLK * LP;
    bf16* Ps = Vt + DHEAD * LP;

    bf16x8_t qfA[2], qfB[2];
    #pragma unroll
    for (int sb = 0; sb < 2; ++sb) {
        const int qrow = (sb ? b2 : a) * 64 + w * 16 + lr;
        const bf16* qp = qkv + (size_t)(b * SEQ + qrow) * NQKV + kv * 64;
        #pragma unroll
        for (int kk = 0; kk < 2; ++kk) {
            bf16x8_t v = *reinterpret_cast<const bf16x8_t*>(qp + kk * 32 + lk);
            if (sb) qfB[kk] = v; else qfA[kk] = v;
        }
    }

    f32x4_t accA[4], accB[4];
    #pragma unroll
    for (int n = 0; n < 4; ++n) {
        accA[n] = (f32x4_t){0.f, 0.f, 0.f, 0.f};
        accB[n] = (f32x4_t){0.f, 0.f, 0.f, 0.f};
    }
    float mA[4] = {-1e30f, -1e30f, -1e30f, -1e30f}, lA[4] = {0.f, 0.f, 0.f, 0.f};
    float mB[4] = {-1e30f, -1e30f, -1e30f, -1e30f}, lB[4] = {0.f, 0.f, 0.f, 0.f};

    const int qcdA = a  * 64 + w * 16 + hi * 4;
    const int qcdB = b2 * 64 + w * 16 + hi * 4;

    auto process = [&](const bf16x8_t* qf, f32x4_t* acc_o, float* m_st,
                       float* l_st, int qcd, int k0g, bool diag) {
        f32x4_t s[4];
        #pragma unroll
        for (int n = 0; n < 4; ++n) s[n] = (f32x4_t){0.f, 0.f, 0.f, 0.f};
        #pragma unroll
        for (int kk = 0; kk < 2; ++kk) {
            #pragma unroll
            for (int n = 0; n < 4; ++n) {
                bf16x8_t kf = *reinterpret_cast<const bf16x8_t*>(&Ks[(n * 16 + lr) * LP + kk * 32 + lk]);
                s[n] = __builtin_amdgcn_mfma_f32_16x16x32_bf16(qf[kk], kf, s[n], 0, 0, 0);
            }
        }
        #pragma unroll
        for (int n = 0; n < 4; ++n) {
            const int colg = k0g + n * 16 + lr;
            #pragma unroll
            for (int j = 0; j < 4; ++j) {
                float val = s[n][j] * 0.125f;
                if (diag && colg > qcd + j) val = -1e30f;
                s[n][j] = val;
            }
        }
        float alpha[4], mnew[4];
        #pragma unroll
        for (int j = 0; j < 4; ++j) {
            float mx = fmaxf(fmaxf(s[0][j], s[1][j]), fmaxf(s[2][j], s[3][j]));
            mx = fmaxf(mx, __shfl_xor(mx, 1));
            mx = fmaxf(mx, __shfl_xor(mx, 2));
            mx = fmaxf(mx, __shfl_xor(mx, 4));
            mx = fmaxf(mx, __shfl_xor(mx, 8));
            mnew[j]  = fmaxf(m_st[j], mx);
            alpha[j] = __expf(m_st[j] - mnew[j]);
            m_st[j]  = mnew[j];
        }
        float psum[4] = {0.f, 0.f, 0.f, 0.f};
        #pragma unroll
        for (int n = 0; n < 4; ++n) {
            #pragma unroll
            for (int j = 0; j < 4; ++j) {
                float p = __expf(s[n][j] - mnew[j]);
                psum[j] += p;
                Ps[(w * 16 + hi * 4 + j) * LP + n * 16 + lr] = __float2bfloat16(p);
            }
        }
        #pragma unroll
        for (int j = 0; j < 4; ++j) {
            float ps = psum[j];
            ps += __shfl_xor(ps, 1);
            ps += __shfl_xor(ps, 2);
            ps += __shfl_xor(ps, 4);
            ps += __shfl_xor(ps, 8);
            l_st[j] = l_st[j] * alpha[j] + ps;
        }
        #pragma unroll
        for (int n = 0; n < 4; ++n)
            #pragma unroll
            for (int j = 0; j < 4; ++j)
                acc_o[n][j] *= alpha[j];
        #pragma unroll
        for (int kk = 0; kk < 2; ++kk) {
            bf16x8_t pa = *reinterpret_cast<const bf16x8_t*>(&Ps[(w * 16 + lr) * LP + kk * 32 + lk]);
            #pragma unroll
            for (int n = 0; n < 4; ++n) {
                bf16x8_t vf = *reinterpret_cast<const bf16x8_t*>(&Vt[(n * 16 + lr) * LP + kk * 32 + lk]);
                acc_o[n] = __builtin_amdgcn_mfma_f32_16x16x32_bf16(pa, vf, acc_o[n], 0, 0, 0);
            }
        }
    };

    for (int kt = 0; kt <= b2; ++kt) {
        const int k0g = kt * KVBLK;
        __syncthreads();
        {
            const int r   = t >> 2;
            const int c16 = (t & 3) * 16;
            const bf16* kb = qkv + (size_t)(b * SEQ + k0g + r) * NQKV + 512 + kv * 64 + c16;
            *reinterpret_cast<bf16x8_t*>(&Ks[r * LP + c16])     = *reinterpret_cast<const bf16x8_t*>(kb);
            *reinterpret_cast<bf16x8_t*>(&Ks[r * LP + c16 + 8]) = *reinterpret_cast<const bf16x8_t*>(kb + 8);
        }
        {
            const int dv = w * 16;
            const bf16* vb = qkv + (size_t)(b * SEQ + k0g + ln) * NQKV + 1024 + kv * 64 + dv;
            bf16x8_t v0 = *reinterpret_cast<const bf16x8_t*>(vb);
            bf16x8_t v1 = *reinterpret_cast<const bf16x8_t*>(vb + 8);
            #pragma unroll
            for (int i = 0; i < 8; ++i) {
                Vt[(dv + i)     * LP + ln] = h_from_b(v0[i]);
                Vt[(dv + 8 + i) * LP + ln] = h_from_b(v1[i]);
            }
        }
        __syncthreads();

        if (kt <= a) process(qfA, accA, mA, lA, qcdA, k0g, kt == a);
        process(qfB, accB, mB, lB, qcdB, k0g, kt == b2);
    }

    #pragma unroll
    for (int j = 0; j < 4; ++j) {
        const float invA = 1.f / lA[j];
        bf16* zpA = z + (size_t)(b * SEQ + qcdA + j) * (NKV * DHEAD) + kv * 64;
        const float invB = 1.f / lB[j];
        bf16* zpB = z + (size_t)(b * SEQ + qcdB + j) * (NKV * DHEAD) + kv * 64;
        #pragma unroll
        for (int n = 0; n < 4; ++n) {
            zpA[n * 16 + lr] = __float2bfloat16(accA[n][j] * invA);
            zpB[n * 16 + lr] = __float2bfloat16(accB[n][j] * invB);
        }
    }
}

// ---------------------------------------------------------------------------
// launch
// ---------------------------------------------------------------------------
extern "C" void kernel_launch(void* const* d_in, const int* in_sizes, int n_in,
                              void* d_out, int out_size, void* d_ws, size_t ws_size,
                              hipStream_t stream)
{
    const float* resid_pre = (const float*)d_in[0];
    const float* W_Q   = (const float*)d_in[1];
    const float* W_K   = (const float*)d_in[2];
    const float* W_V   = (const float*)d_in[3];
    const float* W_O   = (const float*)d_in[4];
    const float* g1    = (const float*)d_in[5];
    const float* b1    = (const float*)d_in[6];
    const float* g2    = (const float*)d_in[7];
    const float* b2    = (const float*)d_in[8];
    const float* W_in  = (const float*)d_in[9];
    const float* b_in  = (const float*)d_in[10];
    const float* W_out = (const float*)d_in[11];
    const float* b_out = (const float*)d_in[12];
    float* out = (float*)d_out;

    char* ws = (char*)d_ws;
    const size_t OFF_WBIG  = 0;                                            // winT (woutT fallback alias)
    const size_t OFF_WOT   = OFF_WBIG + (size_t)DMLP * D_MODEL * 2;
    const size_t OFF_X1    = OFF_WOT  + (size_t)D_MODEL * 512 * 2;
    const size_t OFF_RMID  = OFF_X1   + (size_t)NTOK * D_MODEL * 2;
    const size_t OFF_POST  = OFF_RMID + (size_t)NTOK * D_MODEL * 4;
    const size_t OFF_WQKVT = OFF_POST;                                     // aliased in post
    const size_t OFF_QKV   = OFF_WQKVT + (size_t)NQKV * D_MODEL * 2;
    const size_t OFF_Z     = OFF_QKV   + (size_t)NTOK * NQKV * 2;          // qkv bf16
    const size_t OFF_WOUTT = OFF_POST  + (size_t)NTOK * DMLP * 2;          // dedicated (parallel mode)
    const size_t NEED_PAR  = OFF_WOUTT + (size_t)D_MODEL * DMLP * 2;       // ~186.6 MB (fits: verified R11)

    const bool par = (ws_size >= NEED_PAR);

    bf16*  winT   = (bf16*) (ws + OFF_WBIG);
    bf16*  woutT  = par ? (bf16*)(ws + OFF_WOUTT) : (bf16*)(ws + OFF_WBIG);
    bf16*  woT    = (bf16*) (ws + OFF_WOT);
    bf16*  x1     = (bf16*) (ws + OFF_X1);
    float* rmid   = (float*)(ws + OFF_RMID);
    bf16*  post   = (bf16*) (ws + OFF_POST);
    bf16*  wqkvT  = (bf16*) (ws + OFF_WQKVT);
    bf16*  qkv    = (bf16*) (ws + OFF_QKV);
    bf16*  zbuf   = (bf16*) (ws + OFF_Z);

    // 1. fusedA: rmsnorm1 + wqkvT(Q,K,V group-summed) + woT
    fusedA_kernel<<<4096 + 1536 + 1024, 256, 0, stream>>>(
        resid_pre, g1, b1, x1, W_Q, W_K, W_V, wqkvT, W_O, woT);
    // 2. qkv(bf16) = x1 @ wqkvT^T   [4096 x 1536], K=2048 : 2ph 128x128, grid 384
    gemm_pipe_kernel<128, 128, bf16, false, false, false><<<384, 512, 0, stream>>>(
        x1, wqkvT, qkv, nullptr, nullptr, NTOK, NQKV, D_MODEL, NQKV / 128);
    // 3. fusedB: attention (256 blocks, XCD-pair swizzled) + winT transpose
    fusedB_kernel<<<256 + 16384, 256, 0, stream>>>(qkv, zbuf, W_in, winT);
    // 4. rmid = z @ woT^T + resid_pre   [4096 x 2048], K=512 : 2ph 128x128, grid 512
    gemm_pipe_kernel<128, 128, float, false, false, true><<<512, 512, 0, stream>>>(
        zbuf, woT, rmid, nullptr, resid_pre, NTOK, D_MODEL, 512, D_MODEL / 128);
    // 5. x2 = rmsnorm(rmid) (reuse x1)
    rmsnorm_kernel<<<NTOK, 256, 0, stream>>>(rmid, g2, b2, x1);
    // 6. FFN1 (+ trailing woutT transpose blocks when par): grid 512 GEMM
    //    blocks + 4096 transpose blocks (64x64 tiles of W_out -> woutT).
    gemm_8ph_kernel<bf16, true, true, false><<<512 + (par ? 4096 : 0), 512, 0, stream>>>(
        x1, winT, post, b_in, nullptr, NTOK, DMLP, D_MODEL, DMLP / 256,
        W_out, woutT, 512);
    // 7. fallback only: serial woutT <- W_out (winT dead; same region)
    if (!par)
        transpose_f32_bf16_kernel<<<dim3(D_MODEL / 32, DMLP / 32), 256, 0, stream>>>(W_out, woutT, DMLP, D_MODEL);
    // 8. out = post @ woutT^T + b_out + rmid  [4096 x 2048], K=8192 : 2ph, grid 512
    gemm_pipe_kernel<128, 128, float, true, false, true><<<512, 512, 0, stream>>>(
        post, woutT, out, b_out, rmid, NTOK, D_MODEL, DMLP, D_MODEL / 128);
}

// Round 16
// 453.437 us; speedup vs baseline: 1.0156x; 1.0156x over previous
//
#include <hip/hip_runtime.h>
#include <hip/hip_bf16.h>

// ---------------------------------------------------------------------------
// TransformerBlock forward, MI355X (gfx950).
// B=2, S=2048, D=2048, HQ=32 (group-summed into 8), HKV=8, DH=64, DMLP=8192.
// Round-16: FINAL — exact round-14 configuration (session best, 458.8us).
// Pipeline: fusedA(rmsnorm1+wqkvT+woT) -> QKV 2ph GEMM -> fusedB(attention
// XCD-pair swizzled + winT transpose) -> proj 2ph -> rmsnorm2 ->
// FFN1 8ph(4-barrier) 256^2 -> serial woutT (L3-hot) -> FFN2 2ph.
// ---------------------------------------------------------------------------

using bf16 = __hip_bfloat16;
typedef __bf16 bf16x8_t __attribute__((ext_vector_type(8)));
typedef float  f32x4_t  __attribute__((ext_vector_type(4)));

#define D_MODEL 2048
#define SEQ     2048
#define NB      2
#define NTOK    4096
#define NKV     8
#define DHEAD   64
#define DMLP    8192
#define NQKV    1536

__device__ inline void storev(float* p, float v) { *p = v; }
__device__ inline void storev(bf16* p, float v)  { *p = __float2bfloat16(v); }

__device__ inline bf16 h_from_b(__bf16 x) {
    union { __bf16 b; bf16 h; } u;
    u.b = x;
    return u.h;
}

// ---------------------------------------------------------------------------
// Standalone transpose (woutT, runs right before FFN2 -> L3-hot).
// ---------------------------------------------------------------------------
__global__ __launch_bounds__(256) void transpose_f32_bf16_kernel(
    const float* __restrict__ in, bf16* __restrict__ out, int K, int N)
{
    __shared__ float tile[32][33];
    const int n0 = blockIdx.x * 32, k0 = blockIdx.y * 32;
    const int tx = threadIdx.x & 31, ty = threadIdx.x >> 5;
    #pragma unroll
    for (int i = 0; i < 32; i += 8)
        tile[ty + i][tx] = in[(size_t)(k0 + ty + i) * N + n0 + tx];
    __syncthreads();
    #pragma unroll
    for (int i = 0; i < 32; i += 8)
        out[(size_t)(n0 + ty + i) * K + k0 + tx] = __float2bfloat16(tile[tx][ty + i]);
}

// ---------------------------------------------------------------------------
// Standalone rmsnorm (rmsnorm2).
// ---------------------------------------------------------------------------
__global__ __launch_bounds__(256) void rmsnorm_kernel(
    const float* __restrict__ x, const float* __restrict__ g,
    const float* __restrict__ b, bf16* __restrict__ out)
{
    const int row = blockIdx.x;
    const int t = threadIdx.x;
    const float* xr = x + (size_t)row * D_MODEL;
    float4 a0 = *reinterpret_cast<const float4*>(xr + t * 8);
    float4 a1 = *reinterpret_cast<const float4*>(xr + t * 8 + 4);
    float v[8] = {a0.x, a0.y, a0.z, a0.w, a1.x, a1.y, a1.z, a1.w};
    float sum = 0.f, sumsq = 0.f;
    #pragma unroll
    for (int j = 0; j < 8; ++j) { sum += v[j]; sumsq += v[j] * v[j]; }
    #pragma unroll
    for (int o = 1; o < 64; o <<= 1) {
        sum   += __shfl_xor(sum, o);
        sumsq += __shfl_xor(sumsq, o);
    }
    __shared__ float rs[4], rq[4];
    if ((t & 63) == 0) { rs[t >> 6] = sum; rq[t >> 6] = sumsq; }
    __syncthreads();
    sum   = rs[0] + rs[1] + rs[2] + rs[3];
    sumsq = rq[0] + rq[1] + rq[2] + rq[3];
    const float mu  = sum * (1.f / D_MODEL);
    const float var = sumsq * (1.f / D_MODEL) - mu * mu;
    const float rstd = 1.f / sqrtf(var + 1e-5f);
    const int c = t * 8;
    float4 g0 = *reinterpret_cast<const float4*>(g + c);
    float4 g1 = *reinterpret_cast<const float4*>(g + c + 4);
    float4 b0 = *reinterpret_cast<const float4*>(b + c);
    float4 b1 = *reinterpret_cast<const float4*>(b + c + 4);
    float gg[8] = {g0.x, g0.y, g0.z, g0.w, g1.x, g1.y, g1.z, g1.w};
    float bb[8] = {b0.x, b0.y, b0.z, b0.w, b1.x, b1.y, b1.z, b1.w};
    bf16* op = out + (size_t)row * D_MODEL + c;
    #pragma unroll
    for (int j = 0; j < 8; ++j) op[j] = __float2bfloat16(v[j] * rstd * gg[j] + bb[j]);
}

// ---------------------------------------------------------------------------
// fusedA: blocks [0,4096) rmsnorm1 ; [4096,5632) head-transposes Q/K/V ;
// [5632,6656) woT transpose. 256 thr, 8.3KB LDS union.
// ---------------------------------------------------------------------------
__global__ __launch_bounds__(256) void fusedA_kernel(
    const float* __restrict__ resid_pre, const float* __restrict__ g1,
    const float* __restrict__ b1, bf16* __restrict__ x1,
    const float* __restrict__ WQ, const float* __restrict__ WK,
    const float* __restrict__ WV, bf16* __restrict__ wqkvT,
    const float* __restrict__ WO, bf16* __restrict__ woT)
{
    __shared__ __align__(16) float smem[32 * 65];
    const int id = blockIdx.x;
    const int t  = threadIdx.x;

    if (id < 4096) {
        float* rs = smem;
        float* rq = smem + 4;
        const float* xr = resid_pre + (size_t)id * D_MODEL;
        float4 a0 = *reinterpret_cast<const float4*>(xr + t * 8);
        float4 a1 = *reinterpret_cast<const float4*>(xr + t * 8 + 4);
        float v[8] = {a0.x, a0.y, a0.z, a0.w, a1.x, a1.y, a1.z, a1.w};
        float sum = 0.f, sumsq = 0.f;
        #pragma unroll
        for (int j = 0; j < 8; ++j) { sum += v[j]; sumsq += v[j] * v[j]; }
        #pragma unroll
        for (int o = 1; o < 64; o <<= 1) {
            sum   += __shfl_xor(sum, o);
            sumsq += __shfl_xor(sumsq, o);
        }
        if ((t & 63) == 0) { rs[t >> 6] = sum; rq[t >> 6] = sumsq; }
        __syncthreads();
        sum   = rs[0] + rs[1] + rs[2] + rs[3];
        sumsq = rq[0] + rq[1] + rq[2] + rq[3];
        const float mu  = sum * (1.f / D_MODEL);
        const float var = sumsq * (1.f / D_MODEL) - mu * mu;
        const float rstd = 1.f / sqrtf(var + 1e-5f);
        const int c = t * 8;
        float4 g0 = *reinterpret_cast<const float4*>(g1 + c);
        float4 g1v = *reinterpret_cast<const float4*>(g1 + c + 4);
        float4 b0 = *reinterpret_cast<const float4*>(b1 + c);
        float4 b1v = *reinterpret_cast<const float4*>(b1 + c + 4);
        float gg[8] = {g0.x, g0.y, g0.z, g0.w, g1v.x, g1v.y, g1v.z, g1v.w};
        float bb[8] = {b0.x, b0.y, b0.z, b0.w, b1v.x, b1v.y, b1v.z, b1v.w};
        bf16* op = x1 + (size_t)id * D_MODEL + c;
        #pragma unroll
        for (int j = 0; j < 8; ++j) op[j] = __float2bfloat16(v[j] * rstd * gg[j] + bb[j]);
    } else if (id < 5632) {
        int sub = id - 4096;
        const int which = sub >> 9;
        sub &= 511;
        const float* in = which == 0 ? WQ : (which == 1 ? WK : WV);
        bf16* outp = wqkvT + (size_t)which * 512 * D_MODEL;
        const int ngroup = which == 0 ? 4 : 1;
        const int kv = sub >> 6;
        const int k0 = (sub & 63) * 32;
        float (*tile)[65] = reinterpret_cast<float(*)[65]>(smem);
        const int e  = t & 63, kk = t >> 6;
        #pragma unroll
        for (int i = 0; i < 32; i += 4) {
            float s = 0.f;
            for (int g = 0; g < ngroup; ++g)
                s += in[((size_t)(kv * ngroup + g) * 2048 + k0 + kk + i) * 64 + e];
            tile[kk + i][e] = s;
        }
        __syncthreads();
        const int k = t & 31, ee = t >> 5;
        #pragma unroll
        for (int i = 0; i < 64; i += 8)
            outp[(size_t)(kv * 64 + ee + i) * 2048 + k0 + k] = __float2bfloat16(tile[k][ee + i]);
    } else {
        const int sub = id - 5632;
        const int n0 = (sub & 63) * 32, k0 = (sub >> 6) * 32;
        float (*tile)[33] = reinterpret_cast<float(*)[33]>(smem);
        const int tx = t & 31, ty = t >> 5;
        #pragma unroll
        for (int i = 0; i < 32; i += 8)
            tile[ty + i][tx] = WO[(size_t)(k0 + ty + i) * D_MODEL + n0 + tx];
        __syncthreads();
        #pragma unroll
        for (int i = 0; i < 32; i += 8)
            woT[(size_t)(n0 + ty + i) * 512 + k0 + tx] = __float2bfloat16(tile[tx][ty + i]);
    }
}

// ---------------------------------------------------------------------------
// 2-phase pipelined GEMM (verified): QKV / proj / FFN2.
// ---------------------------------------------------------------------------
template<int BM, int BN, typename TC, bool BIAS, bool RELU, bool RESID>
__global__ __launch_bounds__(512, 2) void gemm_pipe_kernel(
    const bf16* __restrict__ A, const bf16* __restrict__ Bt,
    TC* __restrict__ C, const float* __restrict__ bias,
    const float* __restrict__ resid, int M, int N, int K, int nbx)
{
    constexpr int BK   = 64;
    constexpr int MREP = BM / 32;
    constexpr int NREP = BN / 64;
    constexpr int AI   = (BM * BK) / 4096;
    constexpr int BI   = (BN * BK) / 4096;
    constexpr int LD   = AI + BI;

    __shared__ __align__(16) bf16 As[2][BM * BK];
    __shared__ __align__(16) bf16 Bs[2][BN * BK];

    const int nwg = gridDim.x;
    const int swz = (blockIdx.x & 7) * (nwg >> 3) + (blockIdx.x >> 3);
    const int nby = nwg / nbx;
    const int by  = swz % nby;
    const int bx  = swz / nby;
    const int row0 = by * BM, col0 = bx * BN;

    const int t  = threadIdx.x;
    const int w  = t >> 6, ln = t & 63;
    const int wm = w >> 2, wn = w & 3;
    const int lr = ln & 15, hi = ln >> 4;

    const int srow = w * 8 + (ln >> 3);
    const int skx  = ((ln & 7) ^ (ln >> 3)) * 8;

    f32x4_t acc[MREP][NREP];
    #pragma unroll
    for (int m = 0; m < MREP; ++m)
        #pragma unroll
        for (int n = 0; n < NREP; ++n) acc[m][n] = (f32x4_t){0.f, 0.f, 0.f, 0.f};

    const int NT = K / BK;

    {
        const bf16* ga = A  + (size_t)(row0 + srow) * K + skx;
        const bf16* gb = Bt + (size_t)(col0 + srow) * K + skx;
        #pragma unroll
        for (int i = 0; i < AI; ++i)
            __builtin_amdgcn_global_load_lds(
                (const __attribute__((address_space(1))) void*)(ga + (size_t)i * 64 * K),
                (__attribute__((address_space(3))) void*)(&As[0][i * 4096 + w * 512]), 16, 0, 0);
        #pragma unroll
        for (int i = 0; i < BI; ++i)
            __builtin_amdgcn_global_load_lds(
                (const __attribute__((address_space(1))) void*)(gb + (size_t)i * 64 * K),
                (__attribute__((address_space(3))) void*)(&Bs[0][i * 4096 + w * 512]), 16, 0, 0);
    }

    for (int tt = 0; tt < NT; ++tt) {
        const int c = tt & 1;
        asm volatile("s_waitcnt lgkmcnt(0)" ::: "memory");
        __builtin_amdgcn_sched_barrier(0);
        __builtin_amdgcn_s_barrier();
        __builtin_amdgcn_sched_barrier(0);
        if (tt + 1 < NT) {
            const int d = c ^ 1;
            const int kt = (tt + 1) * BK;
            const bf16* ga = A  + (size_t)(row0 + srow) * K + kt + skx;
            const bf16* gb = Bt + (size_t)(col0 + srow) * K + kt + skx;
            #pragma unroll
            for (int i = 0; i < AI; ++i)
                __builtin_amdgcn_global_load_lds(
                    (const __attribute__((address_space(1))) void*)(ga + (size_t)i * 64 * K),
                    (__attribute__((address_space(3))) void*)(&As[d][i * 4096 + w * 512]), 16, 0, 0);
            #pragma unroll
            for (int i = 0; i < BI; ++i)
                __builtin_amdgcn_global_load_lds(
                    (const __attribute__((address_space(1))) void*)(gb + (size_t)i * 64 * K),
                    (__attribute__((address_space(3))) void*)(&Bs[d][i * 4096 + w * 512]), 16, 0, 0);
            __builtin_amdgcn_sched_barrier(0);
            if constexpr (LD == 8)      asm volatile("s_waitcnt vmcnt(8)" ::: "memory");
            else if constexpr (LD == 6) asm volatile("s_waitcnt vmcnt(6)" ::: "memory");
            else if constexpr (LD == 4) asm volatile("s_waitcnt vmcnt(4)" ::: "memory");
            else                        asm volatile("s_waitcnt vmcnt(3)" ::: "memory");
        } else {
            asm volatile("s_waitcnt vmcnt(0)" ::: "memory");
        }
        __builtin_amdgcn_sched_barrier(0);
        __builtin_amdgcn_s_barrier();
        __builtin_amdgcn_sched_barrier(0);

        #pragma unroll
        for (int kk = 0; kk < 2; ++kk) {
            bf16x8_t af[MREP], bfr[NREP];
            #pragma unroll
            for (int m = 0; m < MREP; ++m) {
                const int row = wm * (BM / 2) + m * 16 + lr;
                af[m] = *reinterpret_cast<const bf16x8_t*>(
                    &As[c][row * 64 + ((kk * 32 + hi * 8) ^ ((row & 7) << 3))]);
            }
            #pragma unroll
            for (int n = 0; n < NREP; ++n) {
                const int col = wn * (BN / 4) + n * 16 + lr;
                bfr[n] = *reinterpret_cast<const bf16x8_t*>(
                    &Bs[c][col * 64 + ((kk * 32 + hi * 8) ^ ((col & 7) << 3))]);
            }
            #pragma unroll
            for (int m = 0; m < MREP; ++m)
                #pragma unroll
                for (int n = 0; n < NREP; ++n)
                    acc[m][n] = __builtin_amdgcn_mfma_f32_16x16x32_bf16(af[m], bfr[n], acc[m][n], 0, 0, 0);
        }
    }

    #pragma unroll
    for (int m = 0; m < MREP; ++m) {
        #pragma unroll
        for (int n = 0; n < NREP; ++n) {
            const int cgl = col0 + wn * (BN / 4) + n * 16 + lr;
            #pragma unroll
            for (int j = 0; j < 4; ++j) {
                const int r = row0 + wm * (BM / 2) + m * 16 + hi * 4 + j;
                float v = acc[m][n][j];
                if constexpr (BIAS)  v += bias[cgl];
                if constexpr (RELU)  v = fmaxf(v, 0.f);
                if constexpr (RESID) v += resid[(size_t)r * N + cgl];
                storev(&C[(size_t)r * N + cgl], v);
            }
        }
    }
}

// ---------------------------------------------------------------------------
// 8-phase 256x256 GEMM for FFN1 (4-barrier variant, round-14 verified).
// ---------------------------------------------------------------------------
template<typename TC, bool BIAS, bool RELU, bool RESID>
__global__ __launch_bounds__(512, 2) void gemm_8ph_kernel(
    const bf16* __restrict__ A, const bf16* __restrict__ Bt,
    TC* __restrict__ C, const float* __restrict__ bias,
    const float* __restrict__ resid, int M, int N, int K, int nbx)
{
    __shared__ __align__(16) bf16 As[2][256 * 64];
    __shared__ __align__(16) bf16 Bs[2][256 * 64];

    const int nwg = gridDim.x;
    const int swz = (blockIdx.x & 7) * (nwg >> 3) + (blockIdx.x >> 3);
    const int nby = nwg / nbx;
    const int by  = swz % nby;
    const int bx  = swz / nby;
    const int row0 = by * 256, col0 = bx * 256;

    const int t  = threadIdx.x;
    const int w  = t >> 6, ln = t & 63;
    const int wm = w >> 2, wn = w & 3;
    const int lr = ln & 15, hi = ln >> 4;
    const int rx = (lr & 7) << 3;

    const int srow = w * 8 + (ln >> 3);
    const int skx  = ((ln & 7) ^ (ln >> 3)) * 8;

#define STAGE_A8(u, dbuf, kt)                                                   \
    __builtin_amdgcn_global_load_lds(                                           \
        (const __attribute__((address_space(1))) void*)(A + (size_t)(row0 + (u) * 64 + srow) * K + (kt) + skx), \
        (__attribute__((address_space(3))) void*)(&As[dbuf][(u) * 4096 + w * 512]), 16, 0, 0)
#define STAGE_B8(u, dbuf, kt)                                                   \
    __builtin_amdgcn_global_load_lds(                                           \
        (const __attribute__((address_space(1))) void*)(Bt + (size_t)(col0 + (u) * 64 + srow) * K + (kt) + skx), \
        (__attribute__((address_space(3))) void*)(&Bs[dbuf][(u) * 4096 + w * 512]), 16, 0, 0)
#define PH_BAR                                                                  \
    __builtin_amdgcn_sched_barrier(0);                                          \
    __builtin_amdgcn_s_barrier();                                               \
    __builtin_amdgcn_sched_barrier(0)
#define LGKM0                                                                   \
    asm volatile("s_waitcnt lgkmcnt(0)" ::: "memory");                          \
    __builtin_amdgcn_sched_barrier(0)

    f32x4_t acc[8][4];
    #pragma unroll
    for (int m = 0; m < 8; ++m)
        #pragma unroll
        for (int n = 0; n < 4; ++n) acc[m][n] = (f32x4_t){0.f, 0.f, 0.f, 0.f};

    bf16x8_t af[4][2];    // mh0 fragments
    bf16x8_t af2[4][2];   // mh1 fragments (separate set: breaks WAR with MFMA)
    bf16x8_t bfr[4][2];

    const int NT = K / 64;

    STAGE_A8(0, 0, 0); STAGE_A8(2, 0, 0);
    STAGE_B8(0, 0, 0); STAGE_B8(1, 0, 0); STAGE_B8(2, 0, 0); STAGE_B8(3, 0, 0);
    STAGE_A8(1, 0, 0); STAGE_A8(3, 0, 0);
    asm volatile("s_waitcnt vmcnt(2)" ::: "memory");
    PH_BAR;

    for (int tt = 0; tt < NT; ++tt) {
        const int c  = tt & 1, d = c ^ 1;
        const int kn = (tt + 1) * 64;
        const bool pf = (tt + 1 < NT);

        // ---- phase 0: reads af(mh0)+bfr(nh0); stage A0,A2 ----
        #pragma unroll
        for (int mq = 0; mq < 4; ++mq) {
            const int row = wm * 128 + mq * 16 + lr;
            #pragma unroll
            for (int kk = 0; kk < 2; ++kk)
                af[mq][kk] = *reinterpret_cast<const bf16x8_t*>(
                    &As[c][row * 64 + ((kk * 32 + hi * 8) ^ rx)]);
        }
        #pragma unroll
        for (int n = 0; n < 2; ++n) {
            const int col = wn * 64 + n * 16 + lr;
            #pragma unroll
            for (int kk = 0; kk < 2; ++kk)
                bfr[n][kk] = *reinterpret_cast<const bf16x8_t*>(
                    &Bs[c][col * 64 + ((kk * 32 + hi * 8) ^ rx)]);
        }
        if (pf) { STAGE_A8(0, d, kn); STAGE_A8(2, d, kn); }
        PH_BAR;
        LGKM0;
        __builtin_amdgcn_s_setprio(1);
        #pragma unroll
        for (int mq = 0; mq < 4; ++mq)
            #pragma unroll
            for (int n = 0; n < 2; ++n)
                #pragma unroll
                for (int kk = 0; kk < 2; ++kk)
                    acc[mq][n] = __builtin_amdgcn_mfma_f32_16x16x32_bf16(af[mq][kk], bfr[n][kk], acc[mq][n], 0, 0, 0);
        __builtin_amdgcn_s_setprio(0);

        // ---- phase 1: reads bfr(nh1); stage B0,B1; gate vmcnt(4) ----
        #pragma unroll
        for (int n = 2; n < 4; ++n) {
            const int col = wn * 64 + n * 16 + lr;
            #pragma unroll
            for (int kk = 0; kk < 2; ++kk)
                bfr[n][kk] = *reinterpret_cast<const bf16x8_t*>(
                    &Bs[c][col * 64 + ((kk * 32 + hi * 8) ^ rx)]);
        }
        if (pf) { STAGE_B8(0, d, kn); STAGE_B8(1, d, kn); }
        __builtin_amdgcn_sched_barrier(0);
        if (pf) { asm volatile("s_waitcnt vmcnt(4)" ::: "memory"); }
        else    { asm volatile("s_waitcnt vmcnt(0)" ::: "memory"); }
        PH_BAR;
        LGKM0;
        __builtin_amdgcn_s_setprio(1);
        #pragma unroll
        for (int mq = 0; mq < 4; ++mq)
            #pragma unroll
            for (int n = 2; n < 4; ++n)
                #pragma unroll
                for (int kk = 0; kk < 2; ++kk)
                    acc[mq][n] = __builtin_amdgcn_mfma_f32_16x16x32_bf16(af[mq][kk], bfr[n][kk], acc[mq][n], 0, 0, 0);
        __builtin_amdgcn_s_setprio(0);

        // ---- phase 2: reads af2(mh1); stage B2,B3 ----
        #pragma unroll
        for (int mq = 0; mq < 4; ++mq) {
            const int row = wm * 128 + 64 + mq * 16 + lr;
            #pragma unroll
            for (int kk = 0; kk < 2; ++kk)
                af2[mq][kk] = *reinterpret_cast<const bf16x8_t*>(
                    &As[c][row * 64 + ((kk * 32 + hi * 8) ^ rx)]);
        }
        if (pf) { STAGE_B8(2, d, kn); STAGE_B8(3, d, kn); }
        PH_BAR;
        LGKM0;
        __builtin_amdgcn_s_setprio(1);
        #pragma unroll
        for (int mq = 0; mq < 4; ++mq)
            #pragma unroll
            for (int n = 2; n < 4; ++n)
                #pragma unroll
                for (int kk = 0; kk < 2; ++kk)
                    acc[4 + mq][n] = __builtin_amdgcn_mfma_f32_16x16x32_bf16(af2[mq][kk], bfr[n][kk], acc[4 + mq][n], 0, 0, 0);
        __builtin_amdgcn_s_setprio(0);

        // ---- phase 3: stage A1,A3; gate vmcnt(2) ----
        if (pf) {
            STAGE_A8(1, d, kn); STAGE_A8(3, d, kn);
            __builtin_amdgcn_sched_barrier(0);
            asm volatile("s_waitcnt vmcnt(2)" ::: "memory");
        }
        PH_BAR;
        __builtin_amdgcn_s_setprio(1);
        #pragma unroll
        for (int mq = 0; mq < 4; ++mq)
            #pragma unroll
            for (int n = 0; n < 2; ++n)
                #pragma unroll
                for (int kk = 0; kk < 2; ++kk)
                    acc[4 + mq][n] = __builtin_amdgcn_mfma_f32_16x16x32_bf16(af2[mq][kk], bfr[n][kk], acc[4 + mq][n], 0, 0, 0);
        __builtin_amdgcn_s_setprio(0);
    }

    #pragma unroll
    for (int m = 0; m < 8; ++m) {
        #pragma unroll
        for (int n = 0; n < 4; ++n) {
            const int cgl = col0 + wn * 64 + n * 16 + lr;
            #pragma unroll
            for (int j = 0; j < 4; ++j) {
                const int r = row0 + wm * 128 + m * 16 + hi * 4 + j;
                float v = acc[m][n][j];
                if constexpr (BIAS)  v += bias[cgl];
                if constexpr (RELU)  v = fmaxf(v, 0.f);
                if constexpr (RESID) v += resid[(size_t)r * N + cgl];
                storev(&C[(size_t)r * N + cgl], v);
            }
        }
    }
#undef STAGE_A8
#undef STAGE_B8
#undef PH_BAR
#undef LGKM0
}

// ---------------------------------------------------------------------------
// fusedB: blocks [0,256) = attention (XCD-pair swizzled) ;
// blocks [256,16640) = winT transpose. 256 thr, 27.6KB LDS union.
// ---------------------------------------------------------------------------
#define KVBLK 64
#define LP    72

__global__ __launch_bounds__(256) void fusedB_kernel(
    const bf16* __restrict__ qkv, bf16* __restrict__ z,
    const float* __restrict__ W_in, bf16* __restrict__ winT)
{
    __shared__ __align__(16) char smem[3 * KVBLK * LP * 2];   // 27648 B

    if (blockIdx.x >= 256) {
        const int sub = blockIdx.x - 256;
        const int n0 = (sub & 255) * 32, k0 = (sub >> 8) * 32;
        float (*tile)[33] = reinterpret_cast<float(*)[33]>(smem);
        const int tx = threadIdx.x & 31, ty = threadIdx.x >> 5;
        #pragma unroll
        for (int i = 0; i < 32; i += 8)
            tile[ty + i][tx] = W_in[(size_t)(k0 + ty + i) * DMLP + n0 + tx];
        __syncthreads();
        #pragma unroll
        for (int i = 0; i < 32; i += 8)
            winT[(size_t)(n0 + ty + i) * D_MODEL + k0 + tx] = __float2bfloat16(tile[tx][ty + i]);
        return;
    }

    const int i_   = blockIdx.x;
    const int pair = (i_ & 7) | ((i_ >> 7) << 3);
    const int a    = (i_ >> 3) & 15;
    const int kv   = pair & 7;
    const int b    = pair >> 3;
    const int b2   = 31 - a;
    const int t  = threadIdx.x;
    const int w  = t >> 6;
    const int ln = t & 63;
    const int lr = ln & 15;
    const int hi = ln >> 4;
    const int lk = hi * 8;

    bf16* Ks = reinterpret_cast<bf16*>(smem);
    bf16* Vt = Ks + KVBLK * LP;
    bf16* Ps = Vt + DHEAD * LP;

    bf16x8_t qfA[2], qfB[2];
    #pragma unroll
    for (int sb = 0; sb < 2; ++sb) {
        const int qrow = (sb ? b2 : a) * 64 + w * 16 + lr;
        const bf16* qp = qkv + (size_t)(b * SEQ + qrow) * NQKV + kv * 64;
        #pragma unroll
        for (int kk = 0; kk < 2; ++kk) {
            bf16x8_t v = *reinterpret_cast<const bf16x8_t*>(qp + kk * 32 + lk);
            if (sb) qfB[kk] = v; else qfA[kk] = v;
        }
    }

    f32x4_t accA[4], accB[4];
    #pragma unroll
    for (int n = 0; n < 4; ++n) {
        accA[n] = (f32x4_t){0.f, 0.f, 0.f, 0.f};
        accB[n] = (f32x4_t){0.f, 0.f, 0.f, 0.f};
    }
    float mA[4] = {-1e30f, -1e30f, -1e30f, -1e30f}, lA[4] = {0.f, 0.f, 0.f, 0.f};
    float mB[4] = {-1e30f, -1e30f, -1e30f, -1e30f}, lB[4] = {0.f, 0.f, 0.f, 0.f};

    const int qcdA = a  * 64 + w * 16 + hi * 4;
    const int qcdB = b2 * 64 + w * 16 + hi * 4;

    auto process = [&](const bf16x8_t* qf, f32x4_t* acc_o, float* m_st,
                       float* l_st, int qcd, int k0g, bool diag) {
        f32x4_t s[4];
        #pragma unroll
        for (int n = 0; n < 4; ++n) s[n] = (f32x4_t){0.f, 0.f, 0.f, 0.f};
        #pragma unroll
        for (int kk = 0; kk < 2; ++kk) {
            #pragma unroll
            for (int n = 0; n < 4; ++n) {
                bf16x8_t kf = *reinterpret_cast<const bf16x8_t*>(&Ks[(n * 16 + lr) * LP + kk * 32 + lk]);
                s[n] = __builtin_amdgcn_mfma_f32_16x16x32_bf16(qf[kk], kf, s[n], 0, 0, 0);
            }
        }
        #pragma unroll
        for (int n = 0; n < 4; ++n) {
            const int colg = k0g + n * 16 + lr;
            #pragma unroll
            for (int j = 0; j < 4; ++j) {
                float val = s[n][j] * 0.125f;
                if (diag && colg > qcd + j) val = -1e30f;
                s[n][j] = val;
            }
        }
        float alpha[4], mnew[4];
        #pragma unroll
        for (int j = 0; j < 4; ++j) {
            float mx = fmaxf(fmaxf(s[0][j], s[1][j]), fmaxf(s[2][j], s[3][j]));
            mx = fmaxf(mx, __shfl_xor(mx, 1));
            mx = fmaxf(mx, __shfl_xor(mx, 2));
            mx = fmaxf(mx, __shfl_xor(mx, 4));
            mx = fmaxf(mx, __shfl_xor(mx, 8));
            mnew[j]  = fmaxf(m_st[j], mx);
            alpha[j] = __expf(m_st[j] - mnew[j]);
            m_st[j]  = mnew[j];
        }
        float psum[4] = {0.f, 0.f, 0.f, 0.f};
        #pragma unroll
        for (int n = 0; n < 4; ++n) {
            #pragma unroll
            for (int j = 0; j < 4; ++j) {
                float p = __expf(s[n][j] - mnew[j]);
                psum[j] += p;
                Ps[(w * 16 + hi * 4 + j) * LP + n * 16 + lr] = __float2bfloat16(p);
            }
        }
        #pragma unroll
        for (int j = 0; j < 4; ++j) {
            float ps = psum[j];
            ps += __shfl_xor(ps, 1);
            ps += __shfl_xor(ps, 2);
            ps += __shfl_xor(ps, 4);
            ps += __shfl_xor(ps, 8);
            l_st[j] = l_st[j] * alpha[j] + ps;
        }
        #pragma unroll
        for (int n = 0; n < 4; ++n)
            #pragma unroll
            for (int j = 0; j < 4; ++j)
                acc_o[n][j] *= alpha[j];
        #pragma unroll
        for (int kk = 0; kk < 2; ++kk) {
            bf16x8_t pa = *reinterpret_cast<const bf16x8_t*>(&Ps[(w * 16 + lr) * LP + kk * 32 + lk]);
            #pragma unroll
            for (int n = 0; n < 4; ++n) {
                bf16x8_t vf = *reinterpret_cast<const bf16x8_t*>(&Vt[(n * 16 + lr) * LP + kk * 32 + lk]);
                acc_o[n] = __builtin_amdgcn_mfma_f32_16x16x32_bf16(pa, vf, acc_o[n], 0, 0, 0);
            }
        }
    };

    for (int kt = 0; kt <= b2; ++kt) {
        const int k0g = kt * KVBLK;
        __syncthreads();
        {
            const int r   = t >> 2;
            const int c16 = (t & 3) * 16;
            const bf16* kb = qkv + (size_t)(b * SEQ + k0g + r) * NQKV + 512 + kv * 64 + c16;
            *reinterpret_cast<bf16x8_t*>(&Ks[r * LP + c16])     = *reinterpret_cast<const bf16x8_t*>(kb);
            *reinterpret_cast<bf16x8_t*>(&Ks[r * LP + c16 + 8]) = *reinterpret_cast<const bf16x8_t*>(kb + 8);
        }
        {
            const int dv = w * 16;
            const bf16* vb = qkv + (size_t)(b * SEQ + k0g + ln) * NQKV + 1024 + kv * 64 + dv;
            bf16x8_t v0 = *reinterpret_cast<const bf16x8_t*>(vb);
            bf16x8_t v1 = *reinterpret_cast<const bf16x8_t*>(vb + 8);
            #pragma unroll
            for (int i = 0; i < 8; ++i) {
                Vt[(dv + i)     * LP + ln] = h_from_b(v0[i]);
                Vt[(dv + 8 + i) * LP + ln] = h_from_b(v1[i]);
            }
        }
        __syncthreads();

        if (kt <= a) process(qfA, accA, mA, lA, qcdA, k0g, kt == a);
        process(qfB, accB, mB, lB, qcdB, k0g, kt == b2);
    }

    #pragma unroll
    for (int j = 0; j < 4; ++j) {
        const float invA = 1.f / lA[j];
        bf16* zpA = z + (size_t)(b * SEQ + qcdA + j) * (NKV * DHEAD) + kv * 64;
        const float invB = 1.f / lB[j];
        bf16* zpB = z + (size_t)(b * SEQ + qcdB + j) * (NKV * DHEAD) + kv * 64;
        #pragma unroll
        for (int n = 0; n < 4; ++n) {
            zpA[n * 16 + lr] = __float2bfloat16(accA[n][j] * invA);
            zpB[n * 16 + lr] = __float2bfloat16(accB[n][j] * invB);
        }
    }
}

// ---------------------------------------------------------------------------
// launch
// ---------------------------------------------------------------------------
extern "C" void kernel_launch(void* const* d_in, const int* in_sizes, int n_in,
                              void* d_out, int out_size, void* d_ws, size_t ws_size,
                              hipStream_t stream)
{
    const float* resid_pre = (const float*)d_in[0];
    const float* W_Q   = (const float*)d_in[1];
    const float* W_K   = (const float*)d_in[2];
    const float* W_V   = (const float*)d_in[3];
    const float* W_O   = (const float*)d_in[4];
    const float* g1    = (const float*)d_in[5];
    const float* b1    = (const float*)d_in[6];
    const float* g2    = (const float*)d_in[7];
    const float* b2    = (const float*)d_in[8];
    const float* W_in  = (const float*)d_in[9];
    const float* b_in  = (const float*)d_in[10];
    const float* W_out = (const float*)d_in[11];
    const float* b_out = (const float*)d_in[12];
    float* out = (float*)d_out;

    char* ws = (char*)d_ws;
    const size_t OFF_WBIG  = 0;                                            // winT / woutT (aliased; woutT after FFN1)
    const size_t OFF_WOT   = OFF_WBIG + (size_t)DMLP * D_MODEL * 2;
    const size_t OFF_X1    = OFF_WOT  + (size_t)D_MODEL * 512 * 2;
    const size_t OFF_RMID  = OFF_X1   + (size_t)NTOK * D_MODEL * 2;
    const size_t OFF_POST  = OFF_RMID + (size_t)NTOK * D_MODEL * 4;
    const size_t OFF_WQKVT = OFF_POST;                                     // aliased in post
    const size_t OFF_QKV   = OFF_WQKVT + (size_t)NQKV * D_MODEL * 2;
    const size_t OFF_Z     = OFF_QKV   + (size_t)NTOK * NQKV * 2;          // qkv bf16

    bf16*  winT   = (bf16*) (ws + OFF_WBIG);
    bf16*  woutT  = (bf16*) (ws + OFF_WBIG);
    bf16*  woT    = (bf16*) (ws + OFF_WOT);
    bf16*  x1     = (bf16*) (ws + OFF_X1);
    float* rmid   = (float*)(ws + OFF_RMID);
    bf16*  post   = (bf16*) (ws + OFF_POST);
    bf16*  wqkvT  = (bf16*) (ws + OFF_WQKVT);
    bf16*  qkv    = (bf16*) (ws + OFF_QKV);
    bf16*  zbuf   = (bf16*) (ws + OFF_Z);

    // 1. fusedA: rmsnorm1 + wqkvT(Q,K,V group-summed) + woT
    fusedA_kernel<<<4096 + 1536 + 1024, 256, 0, stream>>>(
        resid_pre, g1, b1, x1, W_Q, W_K, W_V, wqkvT, W_O, woT);
    // 2. qkv(bf16) = x1 @ wqkvT^T   [4096 x 1536], K=2048 : 2ph 128x128, grid 384
    gemm_pipe_kernel<128, 128, bf16, false, false, false><<<384, 512, 0, stream>>>(
        x1, wqkvT, qkv, nullptr, nullptr, NTOK, NQKV, D_MODEL, NQKV / 128);
    // 3. fusedB: attention (256 blocks, XCD-pair swizzled) + winT transpose
    fusedB_kernel<<<256 + 16384, 256, 0, stream>>>(qkv, zbuf, W_in, winT);
    // 4. rmid = z @ woT^T + resid_pre   [4096 x 2048], K=512 : 2ph 128x128, grid 512
    gemm_pipe_kernel<128, 128, float, false, false, true><<<512, 512, 0, stream>>>(
        zbuf, woT, rmid, nullptr, resid_pre, NTOK, D_MODEL, 512, D_MODEL / 128);
    // 5. x2 = rmsnorm(rmid) (reuse x1)
    rmsnorm_kernel<<<NTOK, 256, 0, stream>>>(rmid, g2, b2, x1);
    // 6. post = relu(x2 @ winT^T + b_in)  [4096 x 8192], K=2048 : 8ph(4-barrier) 256x256, grid 512
    gemm_8ph_kernel<bf16, true, true, false><<<512, 512, 0, stream>>>(
        x1, winT, post, b_in, nullptr, NTOK, DMLP, D_MODEL, DMLP / 256);
    // 7. woutT <- W_out (winT dead; same region; right before FFN2 -> L3-hot)
    transpose_f32_bf16_kernel<<<dim3(D_MODEL / 32, DMLP / 32), 256, 0, stream>>>(W_out, woutT, DMLP, D_MODEL);
    // 8. out = post @ woutT^T + b_out + rmid  [4096 x 2048], K=8192 : 2ph 128x128, grid 512
    gemm_pipe_kernel<128, 128, float, true, false, true><<<512, 512, 0, stream>>>(
        post, woutT, out, b_out, rmid, NTOK, D_MODEL, DMLP, D_MODEL / 128);
}